// Round 2
// baseline (1683.960 us; speedup 1.0000x reference)
//
#include <hip/hip_runtime.h>
#include <math.h>

// ---------------------------------------------------------------------------
// RecurrentGCN: GatedGraphConv(mean,1 layer) + GRUCell + LSTM(1 step, h0=c0=0)
//               + ReLU + Linear(32,1)
// N=100000 nodes, E=6400000 edges, F=4, H_LSTM=32
// ---------------------------------------------------------------------------

__device__ __forceinline__ float fast_sigmoid(float v) {
    return 1.0f / (1.0f + __expf(-v));
}

__device__ __forceinline__ float fast_tanh(float v) {
    // tanh(x) = (e^{2x}-1)/(e^{2x}+1); clamp so __expf never overflows.
    v = fminf(fmaxf(v, -15.0f), 15.0f);
    float t = __expf(2.0f * v);
    return (t - 1.0f) / (t + 1.0f);
}

// m = x @ ggc_w   ([N,4] @ [4,4]); ggc_w row-major [k][j]
__global__ void compute_m_kernel(const float* __restrict__ x,
                                 const float* __restrict__ W,
                                 float* __restrict__ m, int n) {
    int i = blockIdx.x * blockDim.x + threadIdx.x;
    if (i >= n) return;
    float4 xv = reinterpret_cast<const float4*>(x)[i];
    float r0 = xv.x * W[0]  + xv.y * W[4]  + xv.z * W[8]  + xv.w * W[12];
    float r1 = xv.x * W[1]  + xv.y * W[5]  + xv.z * W[9]  + xv.w * W[13];
    float r2 = xv.x * W[2]  + xv.y * W[6]  + xv.z * W[10] + xv.w * W[14];
    float r3 = xv.x * W[3]  + xv.y * W[7]  + xv.z * W[11] + xv.w * W[15];
    reinterpret_cast<float4*>(m)[i] = make_float4(r0, r1, r2, r3);
}

// scatter-add: agg[dst] += m[src]*w ; cnt[dst] += 1
__global__ void edge_agg_kernel(const int* __restrict__ ei,       // [2,E]: src then dst
                                const float* __restrict__ ew,     // [E]
                                const float* __restrict__ m,      // [N,4]
                                float* __restrict__ agg,          // [N,4]
                                float* __restrict__ cnt,          // [N]
                                int E) {
    int e = blockIdx.x * blockDim.x + threadIdx.x;
    if (e >= E) return;
    int s = ei[e];
    int d = ei[E + e];
    float w = ew[e];
    float4 mv = reinterpret_cast<const float4*>(m)[s];
    float* ap = agg + 4 * d;
    unsafeAtomicAdd(ap + 0, mv.x * w);
    unsafeAtomicAdd(ap + 1, mv.y * w);
    unsafeAtomicAdd(ap + 2, mv.z * w);
    unsafeAtomicAdd(ap + 3, mv.w * w);
    unsafeAtomicAdd(cnt + d, 1.0f);
}

// Per-node fused tail: mean, GRU, LSTM(1 step, zero state), ReLU, Linear.
__global__ __launch_bounds__(256) void node_tail_kernel(
    const float* __restrict__ x,          // [N,4]
    const float* __restrict__ agg,        // [N,4]
    const float* __restrict__ cnt,        // [N]
    const float* __restrict__ gru_w_ih,   // [12,4]
    const float* __restrict__ gru_w_hh,   // [12,4]
    const float* __restrict__ gru_b_ih,   // [12]
    const float* __restrict__ gru_b_hh,   // [12]
    const float* __restrict__ lstm_w_ih,  // [128,4]
    const float* __restrict__ lstm_b_ih,  // [128]
    const float* __restrict__ lstm_b_hh,  // [128]
    const float* __restrict__ lin_w,      // [32]
    const float* __restrict__ lin_b,      // [1]
    float* __restrict__ out, int n) {

    __shared__ float s_gwi[48], s_gwh[48], s_gbi[12], s_gbh[12];
    __shared__ float s_lwi[512];   // lstm_w_ih, rows: [i(32), f(32), g(32), o(32)] x 4
    __shared__ float s_lb[128];    // lstm_b_ih + lstm_b_hh
    __shared__ float s_lin[32];
    __shared__ float s_linb;

    int t = threadIdx.x;
    if (t < 48) { s_gwi[t] = gru_w_ih[t]; s_gwh[t] = gru_w_hh[t]; }
    if (t < 12) { s_gbi[t] = gru_b_ih[t]; s_gbh[t] = gru_b_hh[t]; }
    for (int i = t; i < 512; i += 256) s_lwi[i] = lstm_w_ih[i];
    if (t < 128) s_lb[t] = lstm_b_ih[t] + lstm_b_hh[t];
    if (t < 32)  s_lin[t] = lin_w[t];
    if (t == 0)  s_linb = lin_b[0];
    __syncthreads();

    int i = blockIdx.x * blockDim.x + t;
    if (i >= n) return;

    float4 xv = reinterpret_cast<const float4*>(x)[i];
    float4 av = reinterpret_cast<const float4*>(agg)[i];
    float inv = 1.0f / fmaxf(cnt[i], 1.0f);
    float aa[4] = { av.x * inv, av.y * inv, av.z * inv, av.w * inv };
    float xx[4] = { xv.x, xv.y, xv.z, xv.w };

    // GRUCell(agg, x): gi = agg@W_ih^T + b_ih ; gh = x@W_hh^T + b_hh
    float gi[12], gh[12];
    #pragma unroll
    for (int r = 0; r < 12; r++) {
        float s1 = s_gbi[r], s2 = s_gbh[r];
        #pragma unroll
        for (int k = 0; k < 4; k++) {
            s1 += aa[k] * s_gwi[r * 4 + k];
            s2 += xx[k] * s_gwh[r * 4 + k];
        }
        gi[r] = s1; gh[r] = s2;
    }
    float ht[4];
    #pragma unroll
    for (int k = 0; k < 4; k++) {
        float r  = fast_sigmoid(gi[k]     + gh[k]);
        float z  = fast_sigmoid(gi[4 + k] + gh[4 + k]);
        float nc = fast_tanh(gi[8 + k] + r * gh[8 + k]);
        ht[k] = (1.0f - z) * nc + z * xx[k];
    }

    // LSTM single step, zero initial state: f-gate and W_hh are dead.
    // g = ht @ lstm_w_ih^T + (b_ih + b_hh); chunks [i,f,g,o] of 32.
    float acc = s_linb;
    #pragma unroll
    for (int j = 0; j < 32; j++) {
        float vi = s_lb[j], vg = s_lb[64 + j], vo = s_lb[96 + j];
        #pragma unroll
        for (int k = 0; k < 4; k++) {
            vi += ht[k] * s_lwi[j * 4 + k];
            vg += ht[k] * s_lwi[(64 + j) * 4 + k];
            vo += ht[k] * s_lwi[(96 + j) * 4 + k];
        }
        float c = fast_sigmoid(vi) * fast_tanh(vg);
        float h = fast_sigmoid(vo) * fast_tanh(c);
        acc += fmaxf(h, 0.0f) * s_lin[j];
    }
    out[i] = acc;
}

extern "C" void kernel_launch(void* const* d_in, const int* in_sizes, int n_in,
                              void* d_out, int out_size, void* d_ws, size_t ws_size,
                              hipStream_t stream) {
    const float* x         = (const float*)d_in[0];
    const int*   ei        = (const int*)d_in[1];
    const float* ew        = (const float*)d_in[2];
    const float* ggc_w     = (const float*)d_in[3];
    const float* gru_w_ih  = (const float*)d_in[4];
    const float* gru_w_hh  = (const float*)d_in[5];
    const float* gru_b_ih  = (const float*)d_in[6];
    const float* gru_b_hh  = (const float*)d_in[7];
    const float* lstm_w_ih = (const float*)d_in[8];
    // d_in[9] lstm_w_hh: multiplied by h0==0, unused
    const float* lstm_b_ih = (const float*)d_in[10];
    const float* lstm_b_hh = (const float*)d_in[11];
    const float* lin_w     = (const float*)d_in[12];
    const float* lin_b     = (const float*)d_in[13];

    int n = in_sizes[0] / 4;      // 100000
    int E = in_sizes[2];          // 6400000

    // workspace layout: agg[N*4] | cnt[N] | m[N*4]
    float* agg = (float*)d_ws;
    float* cnt = agg + (size_t)n * 4;
    float* m   = cnt + n;

    // zero agg + cnt (ws is re-poisoned to 0xAA before every launch)
    hipMemsetAsync(d_ws, 0, (size_t)n * 5 * sizeof(float), stream);

    compute_m_kernel<<<(n + 255) / 256, 256, 0, stream>>>(x, ggc_w, m, n);
    edge_agg_kernel<<<(E + 255) / 256, 256, 0, stream>>>(ei, ew, m, agg, cnt, E);
    node_tail_kernel<<<(n + 255) / 256, 256, 0, stream>>>(
        x, agg, cnt, gru_w_ih, gru_w_hh, gru_b_ih, gru_b_hh,
        lstm_w_ih, lstm_b_ih, lstm_b_hh, lin_w, lin_b,
        (float*)d_out, n);
}

// Round 5
// 518.016 us; speedup vs baseline: 3.2508x; 3.2508x over previous
//
#include <hip/hip_runtime.h>
#include <math.h>

// ---------------------------------------------------------------------------
// RecurrentGCN: GatedGraphConv(mean,1 layer) + GRUCell + LSTM(1 step, h0=c0=0)
//               + ReLU + Linear(32,1)
// N=100000 nodes, E=6400000 edges, F=4, H_LSTM=32
//
// R3: replace 32M fp32 global atomics (measured: 999MB write-through,
// ~20.5G atomic transactions/s wall, 1567us) with a bucketed counting sort
// (no global atomics) + exclusive-owner per-bucket aggregation fused with
// the node tail.
// ---------------------------------------------------------------------------

#define NBL        128            // nodes per bucket (power of 2)
#define NBL_SHIFT  7
#define B1         512            // partition blocks (hist/scatter); colscan assumes 512
#define SRC_BITS   17             // src < 131072
#define PMAX       1024

__device__ __forceinline__ float fast_sigmoid(float v) {
    return 1.0f / (1.0f + __expf(-v));
}

__device__ __forceinline__ float fast_tanh(float v) {
    v = fminf(fmaxf(v, -15.0f), 15.0f);
    float t = __expf(2.0f * v);
    return (t - 1.0f) / (t + 1.0f);
}

// m = x @ ggc_w   ([N,4] @ [4,4]); ggc_w row-major [k][j]
__global__ void compute_m_kernel(const float* __restrict__ x,
                                 const float* __restrict__ W,
                                 float* __restrict__ m, int n) {
    int i = blockIdx.x * blockDim.x + threadIdx.x;
    if (i >= n) return;
    float4 xv = reinterpret_cast<const float4*>(x)[i];
    float r0 = xv.x * W[0]  + xv.y * W[4]  + xv.z * W[8]  + xv.w * W[12];
    float r1 = xv.x * W[1]  + xv.y * W[5]  + xv.z * W[9]  + xv.w * W[13];
    float r2 = xv.x * W[2]  + xv.y * W[6]  + xv.z * W[10] + xv.w * W[14];
    float r3 = xv.x * W[3]  + xv.y * W[7]  + xv.z * W[11] + xv.w * W[15];
    reinterpret_cast<float4*>(m)[i] = make_float4(r0, r1, r2, r3);
}

// ---- fast path: counting-sort partition --------------------------------

// K2: per-block bucket histogram of dst (no global atomics; writes own row)
__global__ __launch_bounds__(256) void hist_kernel(const int* __restrict__ dst,
                                                   int E, int chunk, int P,
                                                   unsigned* __restrict__ hist2d) {
    __shared__ unsigned h[PMAX];
    int t = threadIdx.x, blk = blockIdx.x;
    for (int i = t; i < P; i += 256) h[i] = 0;
    __syncthreads();
    int lo = blk * chunk, hi = min(lo + chunk, E);
    for (int e = lo + t; e < hi; e += 256)
        atomicAdd(&h[((unsigned)dst[e]) >> NBL_SHIFT], 1u);
    __syncthreads();
    unsigned* row = hist2d + (size_t)blk * P;
    for (int i = t; i < P; i += 256) row[i] = h[i];
}

// K3a: per-bucket exclusive scan down the B1=512 block rows (in place),
//      one wave per bucket; lane L owns rows [8L, 8L+8).
__global__ __launch_bounds__(256) void colscan_kernel(unsigned* __restrict__ hist2d,
                                                      int P,
                                                      unsigned* __restrict__ total) {
    int wave = threadIdx.x >> 6, lane = threadIdx.x & 63;
    int b = blockIdx.x * 4 + wave;
    if (b >= P) return;
    unsigned v[8], s = 0;
    #pragma unroll
    for (int j = 0; j < 8; j++) {
        v[j] = hist2d[(size_t)(lane * 8 + j) * P + b];
        s += v[j];
    }
    unsigned inc = s;
    #pragma unroll
    for (int o = 1; o < 64; o <<= 1) {
        unsigned u = __shfl_up(inc, o);
        if (lane >= o) inc += u;
    }
    unsigned run = inc - s;   // exclusive across lanes
    #pragma unroll
    for (int j = 0; j < 8; j++) {
        hist2d[(size_t)(lane * 8 + j) * P + b] = run;
        run += v[j];
    }
    if (lane == 63) total[b] = inc;
}

// K3b: exclusive scan over P bucket totals -> base[]
__global__ __launch_bounds__(PMAX) void scan_kernel(const unsigned* __restrict__ total,
                                                    int P,
                                                    unsigned* __restrict__ base) {
    __shared__ unsigned s[PMAX];
    int t = threadIdx.x;
    unsigned v = (t < P) ? total[t] : 0u;
    s[t] = v;
    __syncthreads();
    for (int o = 1; o < PMAX; o <<= 1) {
        unsigned u = (t >= o) ? s[t - o] : 0u;
        __syncthreads();
        s[t] += u;
        __syncthreads();
    }
    if (t < P) base[t] = s[t] - v;
}

// K4: place one 8B record per edge at its exact slot.
// slot[bin] starts at base[bin] + colprefix[blk][bin]; LDS atomic allocates.
__global__ __launch_bounds__(256) void scatter_kernel(const int* __restrict__ src,
                                                      const int* __restrict__ dst,
                                                      const float* __restrict__ ew,
                                                      int E, int chunk, int P,
                                                      const unsigned* __restrict__ colprefix,
                                                      const unsigned* __restrict__ base,
                                                      uint2* __restrict__ rec) {
    __shared__ unsigned slot[PMAX];
    int t = threadIdx.x, blk = blockIdx.x;
    const unsigned* row = colprefix + (size_t)blk * P;
    for (int i = t; i < P; i += 256) slot[i] = base[i] + row[i];
    __syncthreads();
    int lo = blk * chunk, hi = min(lo + chunk, E);
    for (int e = lo + t; e < hi; e += 256) {
        unsigned d = (unsigned)dst[e];
        unsigned sA = (unsigned)src[e];
        float w = ew[e];
        unsigned bin = d >> NBL_SHIFT;
        unsigned pos = atomicAdd(&slot[bin], 1u);
        rec[pos] = make_uint2(((d & (NBL - 1)) << SRC_BITS) | sA,
                              __float_as_uint(w));
    }
}

// K5: one block per bucket; exclusive ownership of NBL nodes.
// Stream records -> LDS accumulate -> fused mean/GRU/LSTM/Linear -> out.
__global__ __launch_bounds__(256) void bucket_tail_kernel(
    const uint2* __restrict__ rec,
    const unsigned* __restrict__ base,
    const unsigned* __restrict__ total,
    const float* __restrict__ m,          // [N,4]
    const float* __restrict__ x,          // [N,4]
    const float* __restrict__ gru_w_ih,   // [12,4]
    const float* __restrict__ gru_w_hh,   // [12,4]
    const float* __restrict__ gru_b_ih,   // [12]
    const float* __restrict__ gru_b_hh,   // [12]
    const float* __restrict__ lstm_w_ih,  // [128,4]
    const float* __restrict__ lstm_b_ih,  // [128]
    const float* __restrict__ lstm_b_hh,  // [128]
    const float* __restrict__ lin_w,      // [32]
    const float* __restrict__ lin_b,      // [1]
    float* __restrict__ out, int n) {

    __shared__ float4 bins[NBL];
    __shared__ float  bcnt[NBL];
    __shared__ float s_gwi[48], s_gwh[48], s_gbi[12], s_gbh[12];
    __shared__ float s_lwi[512];
    __shared__ float s_lb[128];
    __shared__ float s_lin[32];
    __shared__ float s_linb;

    int t = threadIdx.x, b = blockIdx.x;

    if (t < NBL) { bins[t] = make_float4(0.f, 0.f, 0.f, 0.f); bcnt[t] = 0.f; }
    if (t < 48) { s_gwi[t] = gru_w_ih[t]; s_gwh[t] = gru_w_hh[t]; }
    if (t < 12) { s_gbi[t] = gru_b_ih[t]; s_gbh[t] = gru_b_hh[t]; }
    for (int i = t; i < 512; i += 256) s_lwi[i] = lstm_w_ih[i];
    if (t < 128) s_lb[t] = lstm_b_ih[t] + lstm_b_hh[t];
    if (t < 32)  s_lin[t] = lin_w[t];
    if (t == 0)  s_linb = lin_b[0];
    __syncthreads();

    unsigned lo = base[b], hi = lo + total[b];
    for (unsigned i = lo + t; i < hi; i += 256) {
        uint2 r = rec[i];
        unsigned srcn = r.x & ((1u << SRC_BITS) - 1u);
        unsigned dl   = r.x >> SRC_BITS;
        float w = __uint_as_float(r.y);
        float4 mv = reinterpret_cast<const float4*>(m)[srcn];
        atomicAdd(&bins[dl].x, mv.x * w);
        atomicAdd(&bins[dl].y, mv.y * w);
        atomicAdd(&bins[dl].z, mv.z * w);
        atomicAdd(&bins[dl].w, mv.w * w);
        atomicAdd(&bcnt[dl], 1.0f);
    }
    __syncthreads();

    int node = b * NBL + t;
    if (t >= NBL || node >= n) return;

    float4 xv = reinterpret_cast<const float4*>(x)[node];
    float4 av = bins[t];
    float inv = 1.0f / fmaxf(bcnt[t], 1.0f);
    float aa[4] = { av.x * inv, av.y * inv, av.z * inv, av.w * inv };
    float xx[4] = { xv.x, xv.y, xv.z, xv.w };

    float gi[12], gh[12];
    #pragma unroll
    for (int r = 0; r < 12; r++) {
        float s1 = s_gbi[r], s2 = s_gbh[r];
        #pragma unroll
        for (int k = 0; k < 4; k++) {
            s1 += aa[k] * s_gwi[r * 4 + k];
            s2 += xx[k] * s_gwh[r * 4 + k];
        }
        gi[r] = s1; gh[r] = s2;
    }
    float ht[4];
    #pragma unroll
    for (int k = 0; k < 4; k++) {
        float r  = fast_sigmoid(gi[k]     + gh[k]);
        float z  = fast_sigmoid(gi[4 + k] + gh[4 + k]);
        float nc = fast_tanh(gi[8 + k] + r * gh[8 + k]);
        ht[k] = (1.0f - z) * nc + z * xx[k];
    }

    float acc = s_linb;
    #pragma unroll
    for (int j = 0; j < 32; j++) {
        float vi = s_lb[j], vg = s_lb[64 + j], vo = s_lb[96 + j];
        #pragma unroll
        for (int k = 0; k < 4; k++) {
            vi += ht[k] * s_lwi[j * 4 + k];
            vg += ht[k] * s_lwi[(64 + j) * 4 + k];
            vo += ht[k] * s_lwi[(96 + j) * 4 + k];
        }
        float c = fast_sigmoid(vi) * fast_tanh(vg);
        float h = fast_sigmoid(vo) * fast_tanh(c);
        acc += fmaxf(h, 0.0f) * s_lin[j];
    }
    out[node] = acc;
}

// ---- fallback path (proven R2 kernels) ---------------------------------

__global__ void edge_agg_kernel(const int* __restrict__ ei,
                                const float* __restrict__ ew,
                                const float* __restrict__ m,
                                float* __restrict__ agg,
                                float* __restrict__ cnt,
                                int E) {
    int e = blockIdx.x * blockDim.x + threadIdx.x;
    if (e >= E) return;
    int s = ei[e];
    int d = ei[E + e];
    float w = ew[e];
    float4 mv = reinterpret_cast<const float4*>(m)[s];
    float* ap = agg + 4 * d;
    unsafeAtomicAdd(ap + 0, mv.x * w);
    unsafeAtomicAdd(ap + 1, mv.y * w);
    unsafeAtomicAdd(ap + 2, mv.z * w);
    unsafeAtomicAdd(ap + 3, mv.w * w);
    unsafeAtomicAdd(cnt + d, 1.0f);
}

__global__ __launch_bounds__(256) void node_tail_kernel(
    const float* __restrict__ x, const float* __restrict__ agg,
    const float* __restrict__ cnt,
    const float* __restrict__ gru_w_ih, const float* __restrict__ gru_w_hh,
    const float* __restrict__ gru_b_ih, const float* __restrict__ gru_b_hh,
    const float* __restrict__ lstm_w_ih, const float* __restrict__ lstm_b_ih,
    const float* __restrict__ lstm_b_hh,
    const float* __restrict__ lin_w, const float* __restrict__ lin_b,
    float* __restrict__ out, int n) {

    __shared__ float s_gwi[48], s_gwh[48], s_gbi[12], s_gbh[12];
    __shared__ float s_lwi[512];
    __shared__ float s_lb[128];
    __shared__ float s_lin[32];
    __shared__ float s_linb;

    int t = threadIdx.x;
    if (t < 48) { s_gwi[t] = gru_w_ih[t]; s_gwh[t] = gru_w_hh[t]; }
    if (t < 12) { s_gbi[t] = gru_b_ih[t]; s_gbh[t] = gru_b_hh[t]; }
    for (int i = t; i < 512; i += 256) s_lwi[i] = lstm_w_ih[i];
    if (t < 128) s_lb[t] = lstm_b_ih[t] + lstm_b_hh[t];
    if (t < 32)  s_lin[t] = lin_w[t];
    if (t == 0)  s_linb = lin_b[0];
    __syncthreads();

    int i = blockIdx.x * blockDim.x + t;
    if (i >= n) return;

    float4 xv = reinterpret_cast<const float4*>(x)[i];
    float4 av = reinterpret_cast<const float4*>(agg)[i];
    float inv = 1.0f / fmaxf(cnt[i], 1.0f);
    float aa[4] = { av.x * inv, av.y * inv, av.z * inv, av.w * inv };
    float xx[4] = { xv.x, xv.y, xv.z, xv.w };

    float gi[12], gh[12];
    #pragma unroll
    for (int r = 0; r < 12; r++) {
        float s1 = s_gbi[r], s2 = s_gbh[r];
        #pragma unroll
        for (int k = 0; k < 4; k++) {
            s1 += aa[k] * s_gwi[r * 4 + k];
            s2 += xx[k] * s_gwh[r * 4 + k];
        }
        gi[r] = s1; gh[r] = s2;
    }
    float ht[4];
    #pragma unroll
    for (int k = 0; k < 4; k++) {
        float r  = fast_sigmoid(gi[k]     + gh[k]);
        float z  = fast_sigmoid(gi[4 + k] + gh[4 + k]);
        float nc = fast_tanh(gi[8 + k] + r * gh[8 + k]);
        ht[k] = (1.0f - z) * nc + z * xx[k];
    }

    float acc = s_linb;
    #pragma unroll
    for (int j = 0; j < 32; j++) {
        float vi = s_lb[j], vg = s_lb[64 + j], vo = s_lb[96 + j];
        #pragma unroll
        for (int k = 0; k < 4; k++) {
            vi += ht[k] * s_lwi[j * 4 + k];
            vg += ht[k] * s_lwi[(64 + j) * 4 + k];
            vo += ht[k] * s_lwi[(96 + j) * 4 + k];
        }
        float c = fast_sigmoid(vi) * fast_tanh(vg);
        float h = fast_sigmoid(vo) * fast_tanh(c);
        acc += fmaxf(h, 0.0f) * s_lin[j];
    }
    out[i] = acc;
}

// ---------------------------------------------------------------------------

extern "C" void kernel_launch(void* const* d_in, const int* in_sizes, int n_in,
                              void* d_out, int out_size, void* d_ws, size_t ws_size,
                              hipStream_t stream) {
    const float* x         = (const float*)d_in[0];
    const int*   ei        = (const int*)d_in[1];
    const float* ew        = (const float*)d_in[2];
    const float* ggc_w     = (const float*)d_in[3];
    const float* gru_w_ih  = (const float*)d_in[4];
    const float* gru_w_hh  = (const float*)d_in[5];
    const float* gru_b_ih  = (const float*)d_in[6];
    const float* gru_b_hh  = (const float*)d_in[7];
    const float* lstm_w_ih = (const float*)d_in[8];
    // d_in[9] lstm_w_hh: multiplied by h0==0, unused
    const float* lstm_b_ih = (const float*)d_in[10];
    const float* lstm_b_hh = (const float*)d_in[11];
    const float* lin_w     = (const float*)d_in[12];
    const float* lin_b     = (const float*)d_in[13];

    int n = in_sizes[0] / 4;      // 100000
    int E = in_sizes[2];          // 6400000
    int P = (n + NBL - 1) >> NBL_SHIFT;

    // fast-path workspace layout (bytes):
    //   rec[E] uint2 | m[n*4] f32 | hist2d[B1*P] u32 | total[P] u32 | base[P] u32
    size_t off_rec  = 0;
    size_t off_m    = off_rec + (size_t)E * 8;
    size_t off_h2d  = off_m + (size_t)n * 16;
    size_t off_tot  = off_h2d + (size_t)B1 * P * 4;
    size_t off_base = off_tot + (size_t)P * 4;
    size_t need     = off_base + (size_t)P * 4;

    bool fast = (ws_size >= need) && (n <= (1 << SRC_BITS)) && (P <= PMAX);

    if (fast) {
        uint2*    rec    = (uint2*)((char*)d_ws + off_rec);
        float*    m      = (float*)((char*)d_ws + off_m);
        unsigned* h2d    = (unsigned*)((char*)d_ws + off_h2d);
        unsigned* totalv = (unsigned*)((char*)d_ws + off_tot);
        unsigned* basev  = (unsigned*)((char*)d_ws + off_base);

        const int* srcp = ei;
        const int* dstp = ei + E;
        int chunk = (E + B1 - 1) / B1;

        compute_m_kernel<<<(n + 255) / 256, 256, 0, stream>>>(x, ggc_w, m, n);
        hist_kernel<<<B1, 256, 0, stream>>>(dstp, E, chunk, P, h2d);
        colscan_kernel<<<(P + 3) / 4, 256, 0, stream>>>(h2d, P, totalv);
        scan_kernel<<<1, PMAX, 0, stream>>>(totalv, P, basev);
        scatter_kernel<<<B1, 256, 0, stream>>>(srcp, dstp, ew, E, chunk, P,
                                               h2d, basev, rec);
        bucket_tail_kernel<<<P, 256, 0, stream>>>(
            rec, basev, totalv, m, x,
            gru_w_ih, gru_w_hh, gru_b_ih, gru_b_hh,
            lstm_w_ih, lstm_b_ih, lstm_b_hh, lin_w, lin_b,
            (float*)d_out, n);
    } else {
        // fallback: proven R2 atomic path
        float* agg = (float*)d_ws;
        float* cnt = agg + (size_t)n * 4;
        float* m   = cnt + n;
        hipMemsetAsync(d_ws, 0, (size_t)n * 5 * sizeof(float), stream);
        compute_m_kernel<<<(n + 255) / 256, 256, 0, stream>>>(x, ggc_w, m, n);
        edge_agg_kernel<<<(E + 255) / 256, 256, 0, stream>>>(ei, ew, m, agg, cnt, E);
        node_tail_kernel<<<(n + 255) / 256, 256, 0, stream>>>(
            x, agg, cnt, gru_w_ih, gru_w_hh, gru_b_ih, gru_b_hh,
            lstm_w_ih, lstm_b_ih, lstm_b_hh, lin_w, lin_b,
            (float*)d_out, n);
    }
}

// Round 8
// 504.476 us; speedup vs baseline: 3.3380x; 1.0268x over previous
//
#include <hip/hip_runtime.h>
#include <math.h>

// ---------------------------------------------------------------------------
// RecurrentGCN: GatedGraphConv(mean,1 layer) + GRUCell + LSTM(1 step, h0=c0=0)
//               + ReLU + Linear(32,1)
// N=100000 nodes, E=6400000 edges, F=4, H_LSTM=32
//
// R6: R5 (counting sort, 518us) was latency-bound:
//  - bucket_tail 228us @ 22.6% occupancy, VALU 4.3%, HBM 1.9% -> 512-thr
//    blocks (24 waves/CU) + 4x unrolled record loop for MLP.
//  - scatter (est ~250us) thrashed L2 write-combining (512 blocks x 782
//    open lines = 6.4MB/XCD > 4MB L2) -> B1=256 (3.2MB/XCD fits).
// ---------------------------------------------------------------------------

#define NBL        128            // nodes per bucket (power of 2)
#define NBL_SHIFT  7
#define B1         256            // partition blocks; colscan assumes B1 = 64*RPL
#define RPL        4              // rows per lane in colscan (B1/64)
#define SRC_BITS   17             // src < 131072
#define PMAX       1024
#define BT         512            // bucket_tail block size

__device__ __forceinline__ float fast_sigmoid(float v) {
    return 1.0f / (1.0f + __expf(-v));
}

__device__ __forceinline__ float fast_tanh(float v) {
    v = fminf(fmaxf(v, -15.0f), 15.0f);
    float t = __expf(2.0f * v);
    return (t - 1.0f) / (t + 1.0f);
}

// m = x @ ggc_w   ([N,4] @ [4,4]); ggc_w row-major [k][j]
__global__ void compute_m_kernel(const float* __restrict__ x,
                                 const float* __restrict__ W,
                                 float* __restrict__ m, int n) {
    int i = blockIdx.x * blockDim.x + threadIdx.x;
    if (i >= n) return;
    float4 xv = reinterpret_cast<const float4*>(x)[i];
    float r0 = xv.x * W[0]  + xv.y * W[4]  + xv.z * W[8]  + xv.w * W[12];
    float r1 = xv.x * W[1]  + xv.y * W[5]  + xv.z * W[9]  + xv.w * W[13];
    float r2 = xv.x * W[2]  + xv.y * W[6]  + xv.z * W[10] + xv.w * W[14];
    float r3 = xv.x * W[3]  + xv.y * W[7]  + xv.z * W[11] + xv.w * W[15];
    reinterpret_cast<float4*>(m)[i] = make_float4(r0, r1, r2, r3);
}

// ---- fast path: counting-sort partition --------------------------------

// K2: per-block bucket histogram of dst (no global atomics; writes own row)
__global__ __launch_bounds__(256) void hist_kernel(const int* __restrict__ dst,
                                                   int E, int chunk, int P,
                                                   unsigned* __restrict__ hist2d) {
    __shared__ unsigned h[PMAX];
    int t = threadIdx.x, blk = blockIdx.x;
    for (int i = t; i < P; i += 256) h[i] = 0;
    __syncthreads();
    int lo = blk * chunk, hi = min(lo + chunk, E);
    for (int e = lo + t; e < hi; e += 256)
        atomicAdd(&h[((unsigned)dst[e]) >> NBL_SHIFT], 1u);
    __syncthreads();
    unsigned* row = hist2d + (size_t)blk * P;
    for (int i = t; i < P; i += 256) row[i] = h[i];
}

// K3a: per-bucket exclusive scan down the B1 block rows (in place),
//      one wave per bucket; lane L owns rows [RPL*L, RPL*L+RPL).
__global__ __launch_bounds__(256) void colscan_kernel(unsigned* __restrict__ hist2d,
                                                      int P,
                                                      unsigned* __restrict__ total) {
    int wave = threadIdx.x >> 6, lane = threadIdx.x & 63;
    int b = blockIdx.x * 4 + wave;
    if (b >= P) return;
    unsigned v[RPL], s = 0;
    #pragma unroll
    for (int j = 0; j < RPL; j++) {
        v[j] = hist2d[(size_t)(lane * RPL + j) * P + b];
        s += v[j];
    }
    unsigned inc = s;
    #pragma unroll
    for (int o = 1; o < 64; o <<= 1) {
        unsigned u = __shfl_up(inc, o);
        if (lane >= o) inc += u;
    }
    unsigned run = inc - s;   // exclusive across lanes
    #pragma unroll
    for (int j = 0; j < RPL; j++) {
        hist2d[(size_t)(lane * RPL + j) * P + b] = run;
        run += v[j];
    }
    if (lane == 63) total[b] = inc;
}

// K3b: exclusive scan over P bucket totals -> base[]
__global__ __launch_bounds__(PMAX) void scan_kernel(const unsigned* __restrict__ total,
                                                    int P,
                                                    unsigned* __restrict__ base) {
    __shared__ unsigned s[PMAX];
    int t = threadIdx.x;
    unsigned v = (t < P) ? total[t] : 0u;
    s[t] = v;
    __syncthreads();
    for (int o = 1; o < PMAX; o <<= 1) {
        unsigned u = (t >= o) ? s[t - o] : 0u;
        __syncthreads();
        s[t] += u;
        __syncthreads();
    }
    if (t < P) base[t] = s[t] - v;
}

// K4: place one 8B record per edge at its exact slot.
// slot[bin] starts at base[bin] + colprefix[blk][bin]; LDS atomic allocates.
__global__ __launch_bounds__(256) void scatter_kernel(const int* __restrict__ src,
                                                      const int* __restrict__ dst,
                                                      const float* __restrict__ ew,
                                                      int E, int chunk, int P,
                                                      const unsigned* __restrict__ colprefix,
                                                      const unsigned* __restrict__ base,
                                                      uint2* __restrict__ rec) {
    __shared__ unsigned slot[PMAX];
    int t = threadIdx.x, blk = blockIdx.x;
    const unsigned* row = colprefix + (size_t)blk * P;
    for (int i = t; i < P; i += 256) slot[i] = base[i] + row[i];
    __syncthreads();
    int lo = blk * chunk, hi = min(lo + chunk, E);
    for (int e = lo + t; e < hi; e += 256) {
        unsigned d = (unsigned)dst[e];
        unsigned sA = (unsigned)src[e];
        float w = ew[e];
        unsigned bin = d >> NBL_SHIFT;
        unsigned pos = atomicAdd(&slot[bin], 1u);
        rec[pos] = make_uint2(((d & (NBL - 1)) << SRC_BITS) | sA,
                              __float_as_uint(w));
    }
}

// K5: one block per bucket; exclusive ownership of NBL nodes.
// Stream records (4x unrolled for MLP) -> LDS accumulate -> fused tail.
__global__ __launch_bounds__(BT) void bucket_tail_kernel(
    const uint2* __restrict__ rec,
    const unsigned* __restrict__ base,
    const unsigned* __restrict__ total,
    const float* __restrict__ m,          // [N,4]
    const float* __restrict__ x,          // [N,4]
    const float* __restrict__ gru_w_ih,   // [12,4]
    const float* __restrict__ gru_w_hh,   // [12,4]
    const float* __restrict__ gru_b_ih,   // [12]
    const float* __restrict__ gru_b_hh,   // [12]
    const float* __restrict__ lstm_w_ih,  // [128,4]
    const float* __restrict__ lstm_b_ih,  // [128]
    const float* __restrict__ lstm_b_hh,  // [128]
    const float* __restrict__ lin_w,      // [32]
    const float* __restrict__ lin_b,      // [1]
    float* __restrict__ out, int n) {

    __shared__ float4 bins[NBL];
    __shared__ float  bcnt[NBL];
    __shared__ float s_gwi[48], s_gwh[48], s_gbi[12], s_gbh[12];
    __shared__ float s_lwi[512];
    __shared__ float s_lb[128];
    __shared__ float s_lin[32];
    __shared__ float s_linb;

    int t = threadIdx.x, b = blockIdx.x;

    if (t < NBL) { bins[t] = make_float4(0.f, 0.f, 0.f, 0.f); bcnt[t] = 0.f; }
    if (t < 48) { s_gwi[t] = gru_w_ih[t]; s_gwh[t] = gru_w_hh[t]; }
    if (t < 12) { s_gbi[t] = gru_b_ih[t]; s_gbh[t] = gru_b_hh[t]; }
    if (t < 512) s_lwi[t] = lstm_w_ih[t];
    if (t < 128) s_lb[t] = lstm_b_ih[t] + lstm_b_hh[t];
    if (t < 32)  s_lin[t] = lin_w[t];
    if (t == 0)  s_linb = lin_b[0];
    __syncthreads();

    unsigned lo = base[b], hi = lo + total[b];
    unsigned i = lo + t;
    const unsigned M = (1u << SRC_BITS) - 1u;

    // main: 4 records in flight per thread
    while (i + 3u * BT < hi) {
        uint2 r0 = rec[i];
        uint2 r1 = rec[i + BT];
        uint2 r2 = rec[i + 2u * BT];
        uint2 r3 = rec[i + 3u * BT];
        float4 m0 = reinterpret_cast<const float4*>(m)[r0.x & M];
        float4 m1 = reinterpret_cast<const float4*>(m)[r1.x & M];
        float4 m2 = reinterpret_cast<const float4*>(m)[r2.x & M];
        float4 m3 = reinterpret_cast<const float4*>(m)[r3.x & M];
        unsigned d0 = r0.x >> SRC_BITS, d1 = r1.x >> SRC_BITS;
        unsigned d2 = r2.x >> SRC_BITS, d3 = r3.x >> SRC_BITS;
        float w0 = __uint_as_float(r0.y), w1 = __uint_as_float(r1.y);
        float w2 = __uint_as_float(r2.y), w3 = __uint_as_float(r3.y);
        atomicAdd(&bins[d0].x, m0.x * w0); atomicAdd(&bins[d0].y, m0.y * w0);
        atomicAdd(&bins[d0].z, m0.z * w0); atomicAdd(&bins[d0].w, m0.w * w0);
        atomicAdd(&bcnt[d0], 1.0f);
        atomicAdd(&bins[d1].x, m1.x * w1); atomicAdd(&bins[d1].y, m1.y * w1);
        atomicAdd(&bins[d1].z, m1.z * w1); atomicAdd(&bins[d1].w, m1.w * w1);
        atomicAdd(&bcnt[d1], 1.0f);
        atomicAdd(&bins[d2].x, m2.x * w2); atomicAdd(&bins[d2].y, m2.y * w2);
        atomicAdd(&bins[d2].z, m2.z * w2); atomicAdd(&bins[d2].w, m2.w * w2);
        atomicAdd(&bcnt[d2], 1.0f);
        atomicAdd(&bins[d3].x, m3.x * w3); atomicAdd(&bins[d3].y, m3.y * w3);
        atomicAdd(&bins[d3].z, m3.z * w3); atomicAdd(&bins[d3].w, m3.w * w3);
        atomicAdd(&bcnt[d3], 1.0f);
        i += 4u * BT;
    }
    for (; i < hi; i += BT) {
        uint2 r = rec[i];
        unsigned srcn = r.x & M;
        unsigned dl   = r.x >> SRC_BITS;
        float w = __uint_as_float(r.y);
        float4 mv = reinterpret_cast<const float4*>(m)[srcn];
        atomicAdd(&bins[dl].x, mv.x * w);
        atomicAdd(&bins[dl].y, mv.y * w);
        atomicAdd(&bins[dl].z, mv.z * w);
        atomicAdd(&bins[dl].w, mv.w * w);
        atomicAdd(&bcnt[dl], 1.0f);
    }
    __syncthreads();

    int node = b * NBL + t;
    if (t >= NBL || node >= n) return;

    float4 xv = reinterpret_cast<const float4*>(x)[node];
    float4 av = bins[t];
    float inv = 1.0f / fmaxf(bcnt[t], 1.0f);
    float aa[4] = { av.x * inv, av.y * inv, av.z * inv, av.w * inv };
    float xx[4] = { xv.x, xv.y, xv.z, xv.w };

    float gi[12], gh[12];
    #pragma unroll
    for (int r = 0; r < 12; r++) {
        float s1 = s_gbi[r], s2 = s_gbh[r];
        #pragma unroll
        for (int k = 0; k < 4; k++) {
            s1 += aa[k] * s_gwi[r * 4 + k];
            s2 += xx[k] * s_gwh[r * 4 + k];
        }
        gi[r] = s1; gh[r] = s2;
    }
    float ht[4];
    #pragma unroll
    for (int k = 0; k < 4; k++) {
        float r  = fast_sigmoid(gi[k]     + gh[k]);
        float z  = fast_sigmoid(gi[4 + k] + gh[4 + k]);
        float nc = fast_tanh(gi[8 + k] + r * gh[8 + k]);
        ht[k] = (1.0f - z) * nc + z * xx[k];
    }

    float acc = s_linb;
    #pragma unroll
    for (int j = 0; j < 32; j++) {
        float vi = s_lb[j], vg = s_lb[64 + j], vo = s_lb[96 + j];
        #pragma unroll
        for (int k = 0; k < 4; k++) {
            vi += ht[k] * s_lwi[j * 4 + k];
            vg += ht[k] * s_lwi[(64 + j) * 4 + k];
            vo += ht[k] * s_lwi[(96 + j) * 4 + k];
        }
        float c = fast_sigmoid(vi) * fast_tanh(vg);
        float h = fast_sigmoid(vo) * fast_tanh(c);
        acc += fmaxf(h, 0.0f) * s_lin[j];
    }
    out[node] = acc;
}

// ---- fallback path (proven R2 kernels) ---------------------------------

__global__ void edge_agg_kernel(const int* __restrict__ ei,
                                const float* __restrict__ ew,
                                const float* __restrict__ m,
                                float* __restrict__ agg,
                                float* __restrict__ cnt,
                                int E) {
    int e = blockIdx.x * blockDim.x + threadIdx.x;
    if (e >= E) return;
    int s = ei[e];
    int d = ei[E + e];
    float w = ew[e];
    float4 mv = reinterpret_cast<const float4*>(m)[s];
    float* ap = agg + 4 * d;
    unsafeAtomicAdd(ap + 0, mv.x * w);
    unsafeAtomicAdd(ap + 1, mv.y * w);
    unsafeAtomicAdd(ap + 2, mv.z * w);
    unsafeAtomicAdd(ap + 3, mv.w * w);
    unsafeAtomicAdd(cnt + d, 1.0f);
}

__global__ __launch_bounds__(256) void node_tail_kernel(
    const float* __restrict__ x, const float* __restrict__ agg,
    const float* __restrict__ cnt,
    const float* __restrict__ gru_w_ih, const float* __restrict__ gru_w_hh,
    const float* __restrict__ gru_b_ih, const float* __restrict__ gru_b_hh,
    const float* __restrict__ lstm_w_ih, const float* __restrict__ lstm_b_ih,
    const float* __restrict__ lstm_b_hh,
    const float* __restrict__ lin_w, const float* __restrict__ lin_b,
    float* __restrict__ out, int n) {

    __shared__ float s_gwi[48], s_gwh[48], s_gbi[12], s_gbh[12];
    __shared__ float s_lwi[512];
    __shared__ float s_lb[128];
    __shared__ float s_lin[32];
    __shared__ float s_linb;

    int t = threadIdx.x;
    if (t < 48) { s_gwi[t] = gru_w_ih[t]; s_gwh[t] = gru_w_hh[t]; }
    if (t < 12) { s_gbi[t] = gru_b_ih[t]; s_gbh[t] = gru_b_hh[t]; }
    for (int i = t; i < 512; i += 256) s_lwi[i] = lstm_w_ih[i];
    if (t < 128) s_lb[t] = lstm_b_ih[t] + lstm_b_hh[t];
    if (t < 32)  s_lin[t] = lin_w[t];
    if (t == 0)  s_linb = lin_b[0];
    __syncthreads();

    int i = blockIdx.x * blockDim.x + t;
    if (i >= n) return;

    float4 xv = reinterpret_cast<const float4*>(x)[i];
    float4 av = reinterpret_cast<const float4*>(agg)[i];
    float inv = 1.0f / fmaxf(cnt[i], 1.0f);
    float aa[4] = { av.x * inv, av.y * inv, av.z * inv, av.w * inv };
    float xx[4] = { xv.x, xv.y, xv.z, xv.w };

    float gi[12], gh[12];
    #pragma unroll
    for (int r = 0; r < 12; r++) {
        float s1 = s_gbi[r], s2 = s_gbh[r];
        #pragma unroll
        for (int k = 0; k < 4; k++) {
            s1 += aa[k] * s_gwi[r * 4 + k];
            s2 += xx[k] * s_gwh[r * 4 + k];
        }
        gi[r] = s1; gh[r] = s2;
    }
    float ht[4];
    #pragma unroll
    for (int k = 0; k < 4; k++) {
        float r  = fast_sigmoid(gi[k]     + gh[k]);
        float z  = fast_sigmoid(gi[4 + k] + gh[4 + k]);
        float nc = fast_tanh(gi[8 + k] + r * gh[8 + k]);
        ht[k] = (1.0f - z) * nc + z * xx[k];
    }

    float acc = s_linb;
    #pragma unroll
    for (int j = 0; j < 32; j++) {
        float vi = s_lb[j], vg = s_lb[64 + j], vo = s_lb[96 + j];
        #pragma unroll
        for (int k = 0; k < 4; k++) {
            vi += ht[k] * s_lwi[j * 4 + k];
            vg += ht[k] * s_lwi[(64 + j) * 4 + k];
            vo += ht[k] * s_lwi[(96 + j) * 4 + k];
        }
        float c = fast_sigmoid(vi) * fast_tanh(vg);
        float h = fast_sigmoid(vo) * fast_tanh(c);
        acc += fmaxf(h, 0.0f) * s_lin[j];
    }
    out[i] = acc;
}

// ---------------------------------------------------------------------------

extern "C" void kernel_launch(void* const* d_in, const int* in_sizes, int n_in,
                              void* d_out, int out_size, void* d_ws, size_t ws_size,
                              hipStream_t stream) {
    const float* x         = (const float*)d_in[0];
    const int*   ei        = (const int*)d_in[1];
    const float* ew        = (const float*)d_in[2];
    const float* ggc_w     = (const float*)d_in[3];
    const float* gru_w_ih  = (const float*)d_in[4];
    const float* gru_w_hh  = (const float*)d_in[5];
    const float* gru_b_ih  = (const float*)d_in[6];
    const float* gru_b_hh  = (const float*)d_in[7];
    const float* lstm_w_ih = (const float*)d_in[8];
    // d_in[9] lstm_w_hh: multiplied by h0==0, unused
    const float* lstm_b_ih = (const float*)d_in[10];
    const float* lstm_b_hh = (const float*)d_in[11];
    const float* lin_w     = (const float*)d_in[12];
    const float* lin_b     = (const float*)d_in[13];

    int n = in_sizes[0] / 4;      // 100000
    int E = in_sizes[2];          // 6400000
    int P = (n + NBL - 1) >> NBL_SHIFT;

    // fast-path workspace layout (bytes):
    //   rec[E] uint2 | m[n*4] f32 | hist2d[B1*P] u32 | total[P] u32 | base[P] u32
    size_t off_rec  = 0;
    size_t off_m    = off_rec + (size_t)E * 8;
    size_t off_h2d  = off_m + (size_t)n * 16;
    size_t off_tot  = off_h2d + (size_t)B1 * P * 4;
    size_t off_base = off_tot + (size_t)P * 4;
    size_t need     = off_base + (size_t)P * 4;

    bool fast = (ws_size >= need) && (n <= (1 << SRC_BITS)) && (P <= PMAX);

    if (fast) {
        uint2*    rec    = (uint2*)((char*)d_ws + off_rec);
        float*    m      = (float*)((char*)d_ws + off_m);
        unsigned* h2d    = (unsigned*)((char*)d_ws + off_h2d);
        unsigned* totalv = (unsigned*)((char*)d_ws + off_tot);
        unsigned* basev  = (unsigned*)((char*)d_ws + off_base);

        const int* srcp = ei;
        const int* dstp = ei + E;
        int chunk = (E + B1 - 1) / B1;

        compute_m_kernel<<<(n + 255) / 256, 256, 0, stream>>>(x, ggc_w, m, n);
        hist_kernel<<<B1, 256, 0, stream>>>(dstp, E, chunk, P, h2d);
        colscan_kernel<<<(P + 3) / 4, 256, 0, stream>>>(h2d, P, totalv);
        scan_kernel<<<1, PMAX, 0, stream>>>(totalv, P, basev);
        scatter_kernel<<<B1, 256, 0, stream>>>(srcp, dstp, ew, E, chunk, P,
                                               h2d, basev, rec);
        bucket_tail_kernel<<<P, BT, 0, stream>>>(
            rec, basev, totalv, m, x,
            gru_w_ih, gru_w_hh, gru_b_ih, gru_b_hh,
            lstm_w_ih, lstm_b_ih, lstm_b_hh, lin_w, lin_b,
            (float*)d_out, n);
    } else {
        // fallback: proven R2 atomic path
        float* agg = (float*)d_ws;
        float* cnt = agg + (size_t)n * 4;
        float* m   = cnt + n;
        hipMemsetAsync(d_ws, 0, (size_t)n * 5 * sizeof(float), stream);
        compute_m_kernel<<<(n + 255) / 256, 256, 0, stream>>>(x, ggc_w, m, n);
        edge_agg_kernel<<<(E + 255) / 256, 256, 0, stream>>>(ei, ew, m, agg, cnt, E);
        node_tail_kernel<<<(n + 255) / 256, 256, 0, stream>>>(
            x, agg, cnt, gru_w_ih, gru_w_hh, gru_b_ih, gru_b_hh,
            lstm_w_ih, lstm_b_ih, lstm_b_hh, lin_w, lin_b,
            (float*)d_out, n);
    }
}

// Round 12
// 341.540 us; speedup vs baseline: 4.9305x; 1.4771x over previous
//
#include <hip/hip_runtime.h>
#include <math.h>

// ---------------------------------------------------------------------------
// RecurrentGCN: GatedGraphConv(mean,1 layer) + GRUCell + LSTM(1 step, h0=c0=0)
//               + ReLU + Linear(32,1)
// N=100000 nodes, E=6400000 edges, F=4, H_LSTM=32
//
// R9: bucket_tail was pinned at 229us by the LDS ATOMIC pipe (32M ds_add_f32
// = 140G/s, occupancy-invariant R5->R8). Replace with per-wave privatized
// bins + 7-ballot duplicate detection + plain ds_read/ds_write RMW
// (wave-program-order safe). Atomic count/record: 5 -> 0.
// ---------------------------------------------------------------------------

#define NBL        128            // nodes per bucket (power of 2)
#define NBL_SHIFT  7
#define B1         256            // partition blocks; colscan assumes B1 = 64*RPL
#define RPL        4              // rows per lane in colscan (B1/64)
#define SRC_BITS   17             // src < 131072
#define PMAX       1024
#define BT         512            // bucket_tail block size
#define NWAVES     (BT/64)

__device__ __forceinline__ float fast_sigmoid(float v) {
    return 1.0f / (1.0f + __expf(-v));
}

__device__ __forceinline__ float fast_tanh(float v) {
    v = fminf(fmaxf(v, -15.0f), 15.0f);
    float t = __expf(2.0f * v);
    return (t - 1.0f) / (t + 1.0f);
}

// m = x @ ggc_w   ([N,4] @ [4,4]); ggc_w row-major [k][j]
__global__ void compute_m_kernel(const float* __restrict__ x,
                                 const float* __restrict__ W,
                                 float* __restrict__ m, int n) {
    int i = blockIdx.x * blockDim.x + threadIdx.x;
    if (i >= n) return;
    float4 xv = reinterpret_cast<const float4*>(x)[i];
    float r0 = xv.x * W[0]  + xv.y * W[4]  + xv.z * W[8]  + xv.w * W[12];
    float r1 = xv.x * W[1]  + xv.y * W[5]  + xv.z * W[9]  + xv.w * W[13];
    float r2 = xv.x * W[2]  + xv.y * W[6]  + xv.z * W[10] + xv.w * W[14];
    float r3 = xv.x * W[3]  + xv.y * W[7]  + xv.z * W[11] + xv.w * W[15];
    reinterpret_cast<float4*>(m)[i] = make_float4(r0, r1, r2, r3);
}

// ---- fast path: counting-sort partition --------------------------------

// K2: per-block bucket histogram of dst
__global__ __launch_bounds__(256) void hist_kernel(const int* __restrict__ dst,
                                                   int E, int chunk, int P,
                                                   unsigned* __restrict__ hist2d) {
    __shared__ unsigned h[PMAX];
    int t = threadIdx.x, blk = blockIdx.x;
    for (int i = t; i < P; i += 256) h[i] = 0;
    __syncthreads();
    int lo = blk * chunk, hi = min(lo + chunk, E);
    for (int e = lo + t; e < hi; e += 256)
        atomicAdd(&h[((unsigned)dst[e]) >> NBL_SHIFT], 1u);
    __syncthreads();
    unsigned* row = hist2d + (size_t)blk * P;
    for (int i = t; i < P; i += 256) row[i] = h[i];
}

// K3a: per-bucket exclusive scan down the B1 block rows (in place)
__global__ __launch_bounds__(256) void colscan_kernel(unsigned* __restrict__ hist2d,
                                                      int P,
                                                      unsigned* __restrict__ total) {
    int wave = threadIdx.x >> 6, lane = threadIdx.x & 63;
    int b = blockIdx.x * 4 + wave;
    if (b >= P) return;
    unsigned v[RPL], s = 0;
    #pragma unroll
    for (int j = 0; j < RPL; j++) {
        v[j] = hist2d[(size_t)(lane * RPL + j) * P + b];
        s += v[j];
    }
    unsigned inc = s;
    #pragma unroll
    for (int o = 1; o < 64; o <<= 1) {
        unsigned u = __shfl_up(inc, o);
        if (lane >= o) inc += u;
    }
    unsigned run = inc - s;
    #pragma unroll
    for (int j = 0; j < RPL; j++) {
        hist2d[(size_t)(lane * RPL + j) * P + b] = run;
        run += v[j];
    }
    if (lane == 63) total[b] = inc;
}

// K3b: exclusive scan over P bucket totals -> base[]
__global__ __launch_bounds__(PMAX) void scan_kernel(const unsigned* __restrict__ total,
                                                    int P,
                                                    unsigned* __restrict__ base) {
    __shared__ unsigned s[PMAX];
    int t = threadIdx.x;
    unsigned v = (t < P) ? total[t] : 0u;
    s[t] = v;
    __syncthreads();
    for (int o = 1; o < PMAX; o <<= 1) {
        unsigned u = (t >= o) ? s[t - o] : 0u;
        __syncthreads();
        s[t] += u;
        __syncthreads();
    }
    if (t < P) base[t] = s[t] - v;
}

// K4: place one 8B record per edge at its exact slot.
__global__ __launch_bounds__(256) void scatter_kernel(const int* __restrict__ src,
                                                      const int* __restrict__ dst,
                                                      const float* __restrict__ ew,
                                                      int E, int chunk, int P,
                                                      const unsigned* __restrict__ colprefix,
                                                      const unsigned* __restrict__ base,
                                                      uint2* __restrict__ rec) {
    __shared__ unsigned slot[PMAX];
    int t = threadIdx.x, blk = blockIdx.x;
    const unsigned* row = colprefix + (size_t)blk * P;
    for (int i = t; i < P; i += 256) slot[i] = base[i] + row[i];
    __syncthreads();
    int lo = blk * chunk, hi = min(lo + chunk, E);
    for (int e = lo + t; e < hi; e += 256) {
        unsigned d = (unsigned)dst[e];
        unsigned sA = (unsigned)src[e];
        float w = ew[e];
        unsigned bin = d >> NBL_SHIFT;
        unsigned pos = atomicAdd(&slot[bin], 1u);
        rec[pos] = make_uint2(((d & (NBL - 1)) << SRC_BITS) | sA,
                              __float_as_uint(w));
    }
}

// K5: one block per bucket. Per-wave privatized bins; duplicate-dl lanes
// serialized via 7-ballot match mask; plain (non-atomic) LDS RMW.
__global__ __launch_bounds__(BT) void bucket_tail_kernel(
    const uint2* __restrict__ rec,
    const unsigned* __restrict__ base,
    const unsigned* __restrict__ total,
    const float* __restrict__ m,          // [N,4]
    const float* __restrict__ x,          // [N,4]
    const float* __restrict__ gru_w_ih,   // [12,4]
    const float* __restrict__ gru_w_hh,   // [12,4]
    const float* __restrict__ gru_b_ih,   // [12]
    const float* __restrict__ gru_b_hh,   // [12]
    const float* __restrict__ lstm_w_ih,  // [128,4]
    const float* __restrict__ lstm_b_ih,  // [128]
    const float* __restrict__ lstm_b_hh,  // [128]
    const float* __restrict__ lin_w,      // [32]
    const float* __restrict__ lin_b,      // [1]
    float* __restrict__ out, int n) {

    __shared__ float4 binsw[NWAVES * NBL];   // 16KB  [wave][node]
    __shared__ float  cntw[NWAVES * NBL];    // 4KB
    __shared__ float s_gwi[48], s_gwh[48], s_gbi[12], s_gbh[12];
    __shared__ float s_lwi[512];
    __shared__ float s_lb[128];
    __shared__ float s_lin[32];
    __shared__ float s_linb;

    int t = threadIdx.x, b = blockIdx.x;
    int lane = t & 63, wv = t >> 6;

    for (int i = t; i < NWAVES * NBL; i += BT) {
        binsw[i] = make_float4(0.f, 0.f, 0.f, 0.f);
        cntw[i] = 0.f;
    }
    if (t < 48) { s_gwi[t] = gru_w_ih[t]; s_gwh[t] = gru_w_hh[t]; }
    if (t < 12) { s_gbi[t] = gru_b_ih[t]; s_gbh[t] = gru_b_hh[t]; }
    if (t < 512) s_lwi[t] = lstm_w_ih[t];
    if (t < 128) s_lb[t] = lstm_b_ih[t] + lstm_b_hh[t];
    if (t < 32)  s_lin[t] = lin_w[t];
    if (t == 0)  s_linb = lin_b[0];
    __syncthreads();

    float4* wb = &binsw[wv * NBL];
    float*  wc = &cntw[wv * NBL];
    const unsigned long long lowmask = (1ull << lane) - 1ull;
    const unsigned M = (1u << SRC_BITS) - 1u;

    unsigned lo = base[b], hi = lo + total[b];
    unsigned i = lo + t;

    // dup-aware plain-RMW accumulate for one record
    #define ACCUM(DL, MV, W)                                              \
    {                                                                     \
        unsigned long long act = __ballot(true);                          \
        unsigned long long mm = act;                                      \
        _Pragma("unroll")                                                 \
        for (int bb = 0; bb < 7; bb++) {                                  \
            bool bit = ((DL >> bb) & 1u) != 0u;                           \
            unsigned long long v = __ballot(bit);                         \
            mm &= bit ? v : ~v;                                           \
        }                                                                 \
        unsigned long long rem = act;                                     \
        while (rem) {                                                     \
            bool mine = (((rem >> lane) & 1ull) != 0ull) &&               \
                        ((mm & rem & lowmask) == 0ull);                   \
            if (mine) {                                                   \
                float4 bv = wb[DL];                                       \
                bv.x += (MV).x * (W); bv.y += (MV).y * (W);               \
                bv.z += (MV).z * (W); bv.w += (MV).w * (W);               \
                wb[DL] = bv;                                              \
                wc[DL] += 1.0f;                                           \
            }                                                             \
            rem &= ~__ballot(mine);                                       \
        }                                                                 \
    }

    // main: 4 records prefetched per thread
    while (i + 3u * BT < hi) {
        uint2 r0 = rec[i];
        uint2 r1 = rec[i + BT];
        uint2 r2 = rec[i + 2u * BT];
        uint2 r3 = rec[i + 3u * BT];
        float4 m0 = reinterpret_cast<const float4*>(m)[r0.x & M];
        float4 m1 = reinterpret_cast<const float4*>(m)[r1.x & M];
        float4 m2 = reinterpret_cast<const float4*>(m)[r2.x & M];
        float4 m3 = reinterpret_cast<const float4*>(m)[r3.x & M];
        unsigned d0 = r0.x >> SRC_BITS, d1 = r1.x >> SRC_BITS;
        unsigned d2 = r2.x >> SRC_BITS, d3 = r3.x >> SRC_BITS;
        float w0 = __uint_as_float(r0.y), w1 = __uint_as_float(r1.y);
        float w2 = __uint_as_float(r2.y), w3 = __uint_as_float(r3.y);
        ACCUM(d0, m0, w0);
        ACCUM(d1, m1, w1);
        ACCUM(d2, m2, w2);
        ACCUM(d3, m3, w3);
        i += 4u * BT;
    }
    for (; i < hi; i += BT) {
        uint2 r = rec[i];
        unsigned dl = r.x >> SRC_BITS;
        float w = __uint_as_float(r.y);
        float4 mv = reinterpret_cast<const float4*>(m)[r.x & M];
        ACCUM(dl, mv, w);
    }
    #undef ACCUM
    __syncthreads();

    int node = b * NBL + t;
    if (t >= NBL || node >= n) return;

    // merge the NWAVES wave-private copies
    float4 av = make_float4(0.f, 0.f, 0.f, 0.f);
    float c = 0.f;
    #pragma unroll
    for (int w8 = 0; w8 < NWAVES; w8++) {
        float4 bv = binsw[w8 * NBL + t];
        av.x += bv.x; av.y += bv.y; av.z += bv.z; av.w += bv.w;
        c += cntw[w8 * NBL + t];
    }

    float4 xv = reinterpret_cast<const float4*>(x)[node];
    float inv = 1.0f / fmaxf(c, 1.0f);
    float aa[4] = { av.x * inv, av.y * inv, av.z * inv, av.w * inv };
    float xx[4] = { xv.x, xv.y, xv.z, xv.w };

    float gi[12], gh[12];
    #pragma unroll
    for (int r = 0; r < 12; r++) {
        float s1 = s_gbi[r], s2 = s_gbh[r];
        #pragma unroll
        for (int k = 0; k < 4; k++) {
            s1 += aa[k] * s_gwi[r * 4 + k];
            s2 += xx[k] * s_gwh[r * 4 + k];
        }
        gi[r] = s1; gh[r] = s2;
    }
    float ht[4];
    #pragma unroll
    for (int k = 0; k < 4; k++) {
        float r  = fast_sigmoid(gi[k]     + gh[k]);
        float z  = fast_sigmoid(gi[4 + k] + gh[4 + k]);
        float nc = fast_tanh(gi[8 + k] + r * gh[8 + k]);
        ht[k] = (1.0f - z) * nc + z * xx[k];
    }

    float acc = s_linb;
    #pragma unroll
    for (int j = 0; j < 32; j++) {
        float vi = s_lb[j], vg = s_lb[64 + j], vo = s_lb[96 + j];
        #pragma unroll
        for (int k = 0; k < 4; k++) {
            vi += ht[k] * s_lwi[j * 4 + k];
            vg += ht[k] * s_lwi[(64 + j) * 4 + k];
            vo += ht[k] * s_lwi[(96 + j) * 4 + k];
        }
        float cc = fast_sigmoid(vi) * fast_tanh(vg);
        float h = fast_sigmoid(vo) * fast_tanh(cc);
        acc += fmaxf(h, 0.0f) * s_lin[j];
    }
    out[node] = acc;
}

// ---- fallback path (proven R2 kernels) ---------------------------------

__global__ void edge_agg_kernel(const int* __restrict__ ei,
                                const float* __restrict__ ew,
                                const float* __restrict__ m,
                                float* __restrict__ agg,
                                float* __restrict__ cnt,
                                int E) {
    int e = blockIdx.x * blockDim.x + threadIdx.x;
    if (e >= E) return;
    int s = ei[e];
    int d = ei[E + e];
    float w = ew[e];
    float4 mv = reinterpret_cast<const float4*>(m)[s];
    float* ap = agg + 4 * d;
    unsafeAtomicAdd(ap + 0, mv.x * w);
    unsafeAtomicAdd(ap + 1, mv.y * w);
    unsafeAtomicAdd(ap + 2, mv.z * w);
    unsafeAtomicAdd(ap + 3, mv.w * w);
    unsafeAtomicAdd(cnt + d, 1.0f);
}

__global__ __launch_bounds__(256) void node_tail_kernel(
    const float* __restrict__ x, const float* __restrict__ agg,
    const float* __restrict__ cnt,
    const float* __restrict__ gru_w_ih, const float* __restrict__ gru_w_hh,
    const float* __restrict__ gru_b_ih, const float* __restrict__ gru_b_hh,
    const float* __restrict__ lstm_w_ih, const float* __restrict__ lstm_b_ih,
    const float* __restrict__ lstm_b_hh,
    const float* __restrict__ lin_w, const float* __restrict__ lin_b,
    float* __restrict__ out, int n) {

    __shared__ float s_gwi[48], s_gwh[48], s_gbi[12], s_gbh[12];
    __shared__ float s_lwi[512];
    __shared__ float s_lb[128];
    __shared__ float s_lin[32];
    __shared__ float s_linb;

    int t = threadIdx.x;
    if (t < 48) { s_gwi[t] = gru_w_ih[t]; s_gwh[t] = gru_w_hh[t]; }
    if (t < 12) { s_gbi[t] = gru_b_ih[t]; s_gbh[t] = gru_b_hh[t]; }
    for (int i = t; i < 512; i += 256) s_lwi[i] = lstm_w_ih[i];
    if (t < 128) s_lb[t] = lstm_b_ih[t] + lstm_b_hh[t];
    if (t < 32)  s_lin[t] = lin_w[t];
    if (t == 0)  s_linb = lin_b[0];
    __syncthreads();

    int i = blockIdx.x * blockDim.x + t;
    if (i >= n) return;

    float4 xv = reinterpret_cast<const float4*>(x)[i];
    float4 av = reinterpret_cast<const float4*>(agg)[i];
    float inv = 1.0f / fmaxf(cnt[i], 1.0f);
    float aa[4] = { av.x * inv, av.y * inv, av.z * inv, av.w * inv };
    float xx[4] = { xv.x, xv.y, xv.z, xv.w };

    float gi[12], gh[12];
    #pragma unroll
    for (int r = 0; r < 12; r++) {
        float s1 = s_gbi[r], s2 = s_gbh[r];
        #pragma unroll
        for (int k = 0; k < 4; k++) {
            s1 += aa[k] * s_gwi[r * 4 + k];
            s2 += xx[k] * s_gwh[r * 4 + k];
        }
        gi[r] = s1; gh[r] = s2;
    }
    float ht[4];
    #pragma unroll
    for (int k = 0; k < 4; k++) {
        float r  = fast_sigmoid(gi[k]     + gh[k]);
        float z  = fast_sigmoid(gi[4 + k] + gh[4 + k]);
        float nc = fast_tanh(gi[8 + k] + r * gh[8 + k]);
        ht[k] = (1.0f - z) * nc + z * xx[k];
    }

    float acc = s_linb;
    #pragma unroll
    for (int j = 0; j < 32; j++) {
        float vi = s_lb[j], vg = s_lb[64 + j], vo = s_lb[96 + j];
        #pragma unroll
        for (int k = 0; k < 4; k++) {
            vi += ht[k] * s_lwi[j * 4 + k];
            vg += ht[k] * s_lwi[(64 + j) * 4 + k];
            vo += ht[k] * s_lwi[(96 + j) * 4 + k];
        }
        float c = fast_sigmoid(vi) * fast_tanh(vg);
        float h = fast_sigmoid(vo) * fast_tanh(c);
        acc += fmaxf(h, 0.0f) * s_lin[j];
    }
    out[i] = acc;
}

// ---------------------------------------------------------------------------

extern "C" void kernel_launch(void* const* d_in, const int* in_sizes, int n_in,
                              void* d_out, int out_size, void* d_ws, size_t ws_size,
                              hipStream_t stream) {
    const float* x         = (const float*)d_in[0];
    const int*   ei        = (const int*)d_in[1];
    const float* ew        = (const float*)d_in[2];
    const float* ggc_w     = (const float*)d_in[3];
    const float* gru_w_ih  = (const float*)d_in[4];
    const float* gru_w_hh  = (const float*)d_in[5];
    const float* gru_b_ih  = (const float*)d_in[6];
    const float* gru_b_hh  = (const float*)d_in[7];
    const float* lstm_w_ih = (const float*)d_in[8];
    // d_in[9] lstm_w_hh: multiplied by h0==0, unused
    const float* lstm_b_ih = (const float*)d_in[10];
    const float* lstm_b_hh = (const float*)d_in[11];
    const float* lin_w     = (const float*)d_in[12];
    const float* lin_b     = (const float*)d_in[13];

    int n = in_sizes[0] / 4;      // 100000
    int E = in_sizes[2];          // 6400000
    int P = (n + NBL - 1) >> NBL_SHIFT;

    // fast-path workspace layout (bytes):
    //   rec[E] uint2 | m[n*4] f32 | hist2d[B1*P] u32 | total[P] u32 | base[P] u32
    size_t off_rec  = 0;
    size_t off_m    = off_rec + (size_t)E * 8;
    size_t off_h2d  = off_m + (size_t)n * 16;
    size_t off_tot  = off_h2d + (size_t)B1 * P * 4;
    size_t off_base = off_tot + (size_t)P * 4;
    size_t need     = off_base + (size_t)P * 4;

    bool fast = (ws_size >= need) && (n <= (1 << SRC_BITS)) && (P <= PMAX);

    if (fast) {
        uint2*    rec    = (uint2*)((char*)d_ws + off_rec);
        float*    m      = (float*)((char*)d_ws + off_m);
        unsigned* h2d    = (unsigned*)((char*)d_ws + off_h2d);
        unsigned* totalv = (unsigned*)((char*)d_ws + off_tot);
        unsigned* basev  = (unsigned*)((char*)d_ws + off_base);

        const int* srcp = ei;
        const int* dstp = ei + E;
        int chunk = (E + B1 - 1) / B1;

        compute_m_kernel<<<(n + 255) / 256, 256, 0, stream>>>(x, ggc_w, m, n);
        hist_kernel<<<B1, 256, 0, stream>>>(dstp, E, chunk, P, h2d);
        colscan_kernel<<<(P + 3) / 4, 256, 0, stream>>>(h2d, P, totalv);
        scan_kernel<<<1, PMAX, 0, stream>>>(totalv, P, basev);
        scatter_kernel<<<B1, 256, 0, stream>>>(srcp, dstp, ew, E, chunk, P,
                                               h2d, basev, rec);
        bucket_tail_kernel<<<P, BT, 0, stream>>>(
            rec, basev, totalv, m, x,
            gru_w_ih, gru_w_hh, gru_b_ih, gru_b_hh,
            lstm_w_ih, lstm_b_ih, lstm_b_hh, lin_w, lin_b,
            (float*)d_out, n);
    } else {
        // fallback: proven R2 atomic path
        float* agg = (float*)d_ws;
        float* cnt = agg + (size_t)n * 4;
        float* m   = cnt + n;
        hipMemsetAsync(d_ws, 0, (size_t)n * 5 * sizeof(float), stream);
        compute_m_kernel<<<(n + 255) / 256, 256, 0, stream>>>(x, ggc_w, m, n);
        edge_agg_kernel<<<(E + 255) / 256, 256, 0, stream>>>(ei, ew, m, agg, cnt, E);
        node_tail_kernel<<<(n + 255) / 256, 256, 0, stream>>>(
            x, agg, cnt, gru_w_ih, gru_w_hh, gru_b_ih, gru_b_hh,
            lstm_w_ih, lstm_b_ih, lstm_b_hh, lin_w, lin_b,
            (float*)d_out, n);
    }
}

// Round 15
// 307.446 us; speedup vs baseline: 5.4773x; 1.1109x over previous
//
#include <hip/hip_runtime.h>
#include <math.h>

// ---------------------------------------------------------------------------
// RecurrentGCN: GatedGraphConv(mean,1 layer) + GRUCell + LSTM(1 step, h0=c0=0)
//               + ReLU + Linear(32,1)
// N=100000 nodes, E=6400000 edges, F=4, H_LSTM=32
//
// R13: scatter was latency-bound (126us @ 9.4% occupancy, 1 block/CU,
// ~49 serial load->atomic->store iters/thread). B1 256->512 (2 blk/CU,
// ws-layout proven in R5) + 4-deep MLP unroll in scatter AND hist.
// bucket_tail keeps R9's ballot/plain-RMW (dropped out of top-5).
// ---------------------------------------------------------------------------

#define NBL        128            // nodes per bucket (power of 2)
#define NBL_SHIFT  7
#define B1         512            // partition blocks; colscan assumes B1 = 64*RPL
#define RPL        8              // rows per lane in colscan (B1/64)
#define SRC_BITS   17             // src < 131072
#define PMAX       1024
#define BT         512            // bucket_tail block size
#define NWAVES     (BT/64)

__device__ __forceinline__ float fast_sigmoid(float v) {
    return 1.0f / (1.0f + __expf(-v));
}

__device__ __forceinline__ float fast_tanh(float v) {
    v = fminf(fmaxf(v, -15.0f), 15.0f);
    float t = __expf(2.0f * v);
    return (t - 1.0f) / (t + 1.0f);
}

// m = x @ ggc_w   ([N,4] @ [4,4]); ggc_w row-major [k][j]
__global__ void compute_m_kernel(const float* __restrict__ x,
                                 const float* __restrict__ W,
                                 float* __restrict__ m, int n) {
    int i = blockIdx.x * blockDim.x + threadIdx.x;
    if (i >= n) return;
    float4 xv = reinterpret_cast<const float4*>(x)[i];
    float r0 = xv.x * W[0]  + xv.y * W[4]  + xv.z * W[8]  + xv.w * W[12];
    float r1 = xv.x * W[1]  + xv.y * W[5]  + xv.z * W[9]  + xv.w * W[13];
    float r2 = xv.x * W[2]  + xv.y * W[6]  + xv.z * W[10] + xv.w * W[14];
    float r3 = xv.x * W[3]  + xv.y * W[7]  + xv.z * W[11] + xv.w * W[15];
    reinterpret_cast<float4*>(m)[i] = make_float4(r0, r1, r2, r3);
}

// ---- fast path: counting-sort partition --------------------------------

// K2: per-block bucket histogram of dst, 4-deep MLP unroll
__global__ __launch_bounds__(256) void hist_kernel(const int* __restrict__ dst,
                                                   int E, int chunk, int P,
                                                   unsigned* __restrict__ hist2d) {
    __shared__ unsigned h[PMAX];
    int t = threadIdx.x, blk = blockIdx.x;
    for (int i = t; i < P; i += 256) h[i] = 0;
    __syncthreads();
    int lo = blk * chunk, hi = min(lo + chunk, E);
    int e = lo + t;
    for (; e + 768 < hi; e += 1024) {
        unsigned d0 = (unsigned)dst[e];
        unsigned d1 = (unsigned)dst[e + 256];
        unsigned d2 = (unsigned)dst[e + 512];
        unsigned d3 = (unsigned)dst[e + 768];
        atomicAdd(&h[d0 >> NBL_SHIFT], 1u);
        atomicAdd(&h[d1 >> NBL_SHIFT], 1u);
        atomicAdd(&h[d2 >> NBL_SHIFT], 1u);
        atomicAdd(&h[d3 >> NBL_SHIFT], 1u);
    }
    for (; e < hi; e += 256)
        atomicAdd(&h[((unsigned)dst[e]) >> NBL_SHIFT], 1u);
    __syncthreads();
    unsigned* row = hist2d + (size_t)blk * P;
    for (int i = t; i < P; i += 256) row[i] = h[i];
}

// K3a: per-bucket exclusive scan down the B1=512 block rows (in place),
//      one wave per bucket; lane L owns rows [8L, 8L+8).  (R5-proven)
__global__ __launch_bounds__(256) void colscan_kernel(unsigned* __restrict__ hist2d,
                                                      int P,
                                                      unsigned* __restrict__ total) {
    int wave = threadIdx.x >> 6, lane = threadIdx.x & 63;
    int b = blockIdx.x * 4 + wave;
    if (b >= P) return;
    unsigned v[RPL], s = 0;
    #pragma unroll
    for (int j = 0; j < RPL; j++) {
        v[j] = hist2d[(size_t)(lane * RPL + j) * P + b];
        s += v[j];
    }
    unsigned inc = s;
    #pragma unroll
    for (int o = 1; o < 64; o <<= 1) {
        unsigned u = __shfl_up(inc, o);
        if (lane >= o) inc += u;
    }
    unsigned run = inc - s;
    #pragma unroll
    for (int j = 0; j < RPL; j++) {
        hist2d[(size_t)(lane * RPL + j) * P + b] = run;
        run += v[j];
    }
    if (lane == 63) total[b] = inc;
}

// K3b: exclusive scan over P bucket totals -> base[]
__global__ __launch_bounds__(PMAX) void scan_kernel(const unsigned* __restrict__ total,
                                                    int P,
                                                    unsigned* __restrict__ base) {
    __shared__ unsigned s[PMAX];
    int t = threadIdx.x;
    unsigned v = (t < P) ? total[t] : 0u;
    s[t] = v;
    __syncthreads();
    for (int o = 1; o < PMAX; o <<= 1) {
        unsigned u = (t >= o) ? s[t - o] : 0u;
        __syncthreads();
        s[t] += u;
        __syncthreads();
    }
    if (t < P) base[t] = s[t] - v;
}

// K4: place one 8B record per edge at its exact slot; 4-deep MLP unroll.
__global__ __launch_bounds__(256) void scatter_kernel(const int* __restrict__ src,
                                                      const int* __restrict__ dst,
                                                      const float* __restrict__ ew,
                                                      int E, int chunk, int P,
                                                      const unsigned* __restrict__ colprefix,
                                                      const unsigned* __restrict__ base,
                                                      uint2* __restrict__ rec) {
    __shared__ unsigned slot[PMAX];
    int t = threadIdx.x, blk = blockIdx.x;
    const unsigned* row = colprefix + (size_t)blk * P;
    for (int i = t; i < P; i += 256) slot[i] = base[i] + row[i];
    __syncthreads();
    int lo = blk * chunk, hi = min(lo + chunk, E);
    int e = lo + t;
    for (; e + 768 < hi; e += 1024) {
        unsigned d0 = (unsigned)dst[e];
        unsigned d1 = (unsigned)dst[e + 256];
        unsigned d2 = (unsigned)dst[e + 512];
        unsigned d3 = (unsigned)dst[e + 768];
        unsigned s0 = (unsigned)src[e];
        unsigned s1 = (unsigned)src[e + 256];
        unsigned s2 = (unsigned)src[e + 512];
        unsigned s3 = (unsigned)src[e + 768];
        float w0 = ew[e];
        float w1 = ew[e + 256];
        float w2 = ew[e + 512];
        float w3 = ew[e + 768];
        unsigned p0 = atomicAdd(&slot[d0 >> NBL_SHIFT], 1u);
        unsigned p1 = atomicAdd(&slot[d1 >> NBL_SHIFT], 1u);
        unsigned p2 = atomicAdd(&slot[d2 >> NBL_SHIFT], 1u);
        unsigned p3 = atomicAdd(&slot[d3 >> NBL_SHIFT], 1u);
        rec[p0] = make_uint2(((d0 & (NBL - 1)) << SRC_BITS) | s0, __float_as_uint(w0));
        rec[p1] = make_uint2(((d1 & (NBL - 1)) << SRC_BITS) | s1, __float_as_uint(w1));
        rec[p2] = make_uint2(((d2 & (NBL - 1)) << SRC_BITS) | s2, __float_as_uint(w2));
        rec[p3] = make_uint2(((d3 & (NBL - 1)) << SRC_BITS) | s3, __float_as_uint(w3));
    }
    for (; e < hi; e += 256) {
        unsigned d = (unsigned)dst[e];
        unsigned sA = (unsigned)src[e];
        float w = ew[e];
        unsigned pos = atomicAdd(&slot[d >> NBL_SHIFT], 1u);
        rec[pos] = make_uint2(((d & (NBL - 1)) << SRC_BITS) | sA,
                              __float_as_uint(w));
    }
}

// K5: one block per bucket. Per-wave privatized bins; duplicate-dl lanes
// serialized via 7-ballot match mask; plain (non-atomic) LDS RMW. (R12-proven)
__global__ __launch_bounds__(BT) void bucket_tail_kernel(
    const uint2* __restrict__ rec,
    const unsigned* __restrict__ base,
    const unsigned* __restrict__ total,
    const float* __restrict__ m,          // [N,4]
    const float* __restrict__ x,          // [N,4]
    const float* __restrict__ gru_w_ih,   // [12,4]
    const float* __restrict__ gru_w_hh,   // [12,4]
    const float* __restrict__ gru_b_ih,   // [12]
    const float* __restrict__ gru_b_hh,   // [12]
    const float* __restrict__ lstm_w_ih,  // [128,4]
    const float* __restrict__ lstm_b_ih,  // [128]
    const float* __restrict__ lstm_b_hh,  // [128]
    const float* __restrict__ lin_w,      // [32]
    const float* __restrict__ lin_b,      // [1]
    float* __restrict__ out, int n) {

    __shared__ float4 binsw[NWAVES * NBL];   // 16KB  [wave][node]
    __shared__ float  cntw[NWAVES * NBL];    // 4KB
    __shared__ float s_gwi[48], s_gwh[48], s_gbi[12], s_gbh[12];
    __shared__ float s_lwi[512];
    __shared__ float s_lb[128];
    __shared__ float s_lin[32];
    __shared__ float s_linb;

    int t = threadIdx.x, b = blockIdx.x;
    int lane = t & 63, wv = t >> 6;

    for (int i = t; i < NWAVES * NBL; i += BT) {
        binsw[i] = make_float4(0.f, 0.f, 0.f, 0.f);
        cntw[i] = 0.f;
    }
    if (t < 48) { s_gwi[t] = gru_w_ih[t]; s_gwh[t] = gru_w_hh[t]; }
    if (t < 12) { s_gbi[t] = gru_b_ih[t]; s_gbh[t] = gru_b_hh[t]; }
    if (t < 512) s_lwi[t] = lstm_w_ih[t];
    if (t < 128) s_lb[t] = lstm_b_ih[t] + lstm_b_hh[t];
    if (t < 32)  s_lin[t] = lin_w[t];
    if (t == 0)  s_linb = lin_b[0];
    __syncthreads();

    float4* wb = &binsw[wv * NBL];
    float*  wc = &cntw[wv * NBL];
    const unsigned long long lowmask = (1ull << lane) - 1ull;
    const unsigned M = (1u << SRC_BITS) - 1u;

    unsigned lo = base[b], hi = lo + total[b];
    unsigned i = lo + t;

    // dup-aware plain-RMW accumulate for one record
    #define ACCUM(DL, MV, W)                                              \
    {                                                                     \
        unsigned long long act = __ballot(true);                          \
        unsigned long long mm = act;                                      \
        _Pragma("unroll")                                                 \
        for (int bb = 0; bb < 7; bb++) {                                  \
            bool bit = ((DL >> bb) & 1u) != 0u;                           \
            unsigned long long v = __ballot(bit);                         \
            mm &= bit ? v : ~v;                                           \
        }                                                                 \
        unsigned long long rem = act;                                     \
        while (rem) {                                                     \
            bool mine = (((rem >> lane) & 1ull) != 0ull) &&               \
                        ((mm & rem & lowmask) == 0ull);                   \
            if (mine) {                                                   \
                float4 bv = wb[DL];                                       \
                bv.x += (MV).x * (W); bv.y += (MV).y * (W);               \
                bv.z += (MV).z * (W); bv.w += (MV).w * (W);               \
                wb[DL] = bv;                                              \
                wc[DL] += 1.0f;                                           \
            }                                                             \
            rem &= ~__ballot(mine);                                       \
        }                                                                 \
    }

    // main: 4 records prefetched per thread
    while (i + 3u * BT < hi) {
        uint2 r0 = rec[i];
        uint2 r1 = rec[i + BT];
        uint2 r2 = rec[i + 2u * BT];
        uint2 r3 = rec[i + 3u * BT];
        float4 m0 = reinterpret_cast<const float4*>(m)[r0.x & M];
        float4 m1 = reinterpret_cast<const float4*>(m)[r1.x & M];
        float4 m2 = reinterpret_cast<const float4*>(m)[r2.x & M];
        float4 m3 = reinterpret_cast<const float4*>(m)[r3.x & M];
        unsigned d0 = r0.x >> SRC_BITS, d1 = r1.x >> SRC_BITS;
        unsigned d2 = r2.x >> SRC_BITS, d3 = r3.x >> SRC_BITS;
        float w0 = __uint_as_float(r0.y), w1 = __uint_as_float(r1.y);
        float w2 = __uint_as_float(r2.y), w3 = __uint_as_float(r3.y);
        ACCUM(d0, m0, w0);
        ACCUM(d1, m1, w1);
        ACCUM(d2, m2, w2);
        ACCUM(d3, m3, w3);
        i += 4u * BT;
    }
    for (; i < hi; i += BT) {
        uint2 r = rec[i];
        unsigned dl = r.x >> SRC_BITS;
        float w = __uint_as_float(r.y);
        float4 mv = reinterpret_cast<const float4*>(m)[r.x & M];
        ACCUM(dl, mv, w);
    }
    #undef ACCUM
    __syncthreads();

    int node = b * NBL + t;
    if (t >= NBL || node >= n) return;

    // merge the NWAVES wave-private copies
    float4 av = make_float4(0.f, 0.f, 0.f, 0.f);
    float c = 0.f;
    #pragma unroll
    for (int w8 = 0; w8 < NWAVES; w8++) {
        float4 bv = binsw[w8 * NBL + t];
        av.x += bv.x; av.y += bv.y; av.z += bv.z; av.w += bv.w;
        c += cntw[w8 * NBL + t];
    }

    float4 xv = reinterpret_cast<const float4*>(x)[node];
    float inv = 1.0f / fmaxf(c, 1.0f);
    float aa[4] = { av.x * inv, av.y * inv, av.z * inv, av.w * inv };
    float xx[4] = { xv.x, xv.y, xv.z, xv.w };

    float gi[12], gh[12];
    #pragma unroll
    for (int r = 0; r < 12; r++) {
        float s1 = s_gbi[r], s2 = s_gbh[r];
        #pragma unroll
        for (int k = 0; k < 4; k++) {
            s1 += aa[k] * s_gwi[r * 4 + k];
            s2 += xx[k] * s_gwh[r * 4 + k];
        }
        gi[r] = s1; gh[r] = s2;
    }
    float ht[4];
    #pragma unroll
    for (int k = 0; k < 4; k++) {
        float r  = fast_sigmoid(gi[k]     + gh[k]);
        float z  = fast_sigmoid(gi[4 + k] + gh[4 + k]);
        float nc = fast_tanh(gi[8 + k] + r * gh[8 + k]);
        ht[k] = (1.0f - z) * nc + z * xx[k];
    }

    float acc = s_linb;
    #pragma unroll
    for (int j = 0; j < 32; j++) {
        float vi = s_lb[j], vg = s_lb[64 + j], vo = s_lb[96 + j];
        #pragma unroll
        for (int k = 0; k < 4; k++) {
            vi += ht[k] * s_lwi[j * 4 + k];
            vg += ht[k] * s_lwi[(64 + j) * 4 + k];
            vo += ht[k] * s_lwi[(96 + j) * 4 + k];
        }
        float cc = fast_sigmoid(vi) * fast_tanh(vg);
        float h = fast_sigmoid(vo) * fast_tanh(cc);
        acc += fmaxf(h, 0.0f) * s_lin[j];
    }
    out[node] = acc;
}

// ---- fallback path (proven R2 kernels) ---------------------------------

__global__ void edge_agg_kernel(const int* __restrict__ ei,
                                const float* __restrict__ ew,
                                const float* __restrict__ m,
                                float* __restrict__ agg,
                                float* __restrict__ cnt,
                                int E) {
    int e = blockIdx.x * blockDim.x + threadIdx.x;
    if (e >= E) return;
    int s = ei[e];
    int d = ei[E + e];
    float w = ew[e];
    float4 mv = reinterpret_cast<const float4*>(m)[s];
    float* ap = agg + 4 * d;
    unsafeAtomicAdd(ap + 0, mv.x * w);
    unsafeAtomicAdd(ap + 1, mv.y * w);
    unsafeAtomicAdd(ap + 2, mv.z * w);
    unsafeAtomicAdd(ap + 3, mv.w * w);
    unsafeAtomicAdd(cnt + d, 1.0f);
}

__global__ __launch_bounds__(256) void node_tail_kernel(
    const float* __restrict__ x, const float* __restrict__ agg,
    const float* __restrict__ cnt,
    const float* __restrict__ gru_w_ih, const float* __restrict__ gru_w_hh,
    const float* __restrict__ gru_b_ih, const float* __restrict__ gru_b_hh,
    const float* __restrict__ lstm_w_ih, const float* __restrict__ lstm_b_ih,
    const float* __restrict__ lstm_b_hh,
    const float* __restrict__ lin_w, const float* __restrict__ lin_b,
    float* __restrict__ out, int n) {

    __shared__ float s_gwi[48], s_gwh[48], s_gbi[12], s_gbh[12];
    __shared__ float s_lwi[512];
    __shared__ float s_lb[128];
    __shared__ float s_lin[32];
    __shared__ float s_linb;

    int t = threadIdx.x;
    if (t < 48) { s_gwi[t] = gru_w_ih[t]; s_gwh[t] = gru_w_hh[t]; }
    if (t < 12) { s_gbi[t] = gru_b_ih[t]; s_gbh[t] = gru_b_hh[t]; }
    for (int i = t; i < 512; i += 256) s_lwi[i] = lstm_w_ih[i];
    if (t < 128) s_lb[t] = lstm_b_ih[t] + lstm_b_hh[t];
    if (t < 32)  s_lin[t] = lin_w[t];
    if (t == 0)  s_linb = lin_b[0];
    __syncthreads();

    int i = blockIdx.x * blockDim.x + t;
    if (i >= n) return;

    float4 xv = reinterpret_cast<const float4*>(x)[i];
    float4 av = reinterpret_cast<const float4*>(agg)[i];
    float inv = 1.0f / fmaxf(cnt[i], 1.0f);
    float aa[4] = { av.x * inv, av.y * inv, av.z * inv, av.w * inv };
    float xx[4] = { xv.x, xv.y, xv.z, xv.w };

    float gi[12], gh[12];
    #pragma unroll
    for (int r = 0; r < 12; r++) {
        float s1 = s_gbi[r], s2 = s_gbh[r];
        #pragma unroll
        for (int k = 0; k < 4; k++) {
            s1 += aa[k] * s_gwi[r * 4 + k];
            s2 += xx[k] * s_gwh[r * 4 + k];
        }
        gi[r] = s1; gh[r] = s2;
    }
    float ht[4];
    #pragma unroll
    for (int k = 0; k < 4; k++) {
        float r  = fast_sigmoid(gi[k]     + gh[k]);
        float z  = fast_sigmoid(gi[4 + k] + gh[4 + k]);
        float nc = fast_tanh(gi[8 + k] + r * gh[8 + k]);
        ht[k] = (1.0f - z) * nc + z * xx[k];
    }

    float acc = s_linb;
    #pragma unroll
    for (int j = 0; j < 32; j++) {
        float vi = s_lb[j], vg = s_lb[64 + j], vo = s_lb[96 + j];
        #pragma unroll
        for (int k = 0; k < 4; k++) {
            vi += ht[k] * s_lwi[j * 4 + k];
            vg += ht[k] * s_lwi[(64 + j) * 4 + k];
            vo += ht[k] * s_lwi[(96 + j) * 4 + k];
        }
        float c = fast_sigmoid(vi) * fast_tanh(vg);
        float h = fast_sigmoid(vo) * fast_tanh(c);
        acc += fmaxf(h, 0.0f) * s_lin[j];
    }
    out[i] = acc;
}

// ---------------------------------------------------------------------------

extern "C" void kernel_launch(void* const* d_in, const int* in_sizes, int n_in,
                              void* d_out, int out_size, void* d_ws, size_t ws_size,
                              hipStream_t stream) {
    const float* x         = (const float*)d_in[0];
    const int*   ei        = (const int*)d_in[1];
    const float* ew        = (const float*)d_in[2];
    const float* ggc_w     = (const float*)d_in[3];
    const float* gru_w_ih  = (const float*)d_in[4];
    const float* gru_w_hh  = (const float*)d_in[5];
    const float* gru_b_ih  = (const float*)d_in[6];
    const float* gru_b_hh  = (const float*)d_in[7];
    const float* lstm_w_ih = (const float*)d_in[8];
    // d_in[9] lstm_w_hh: multiplied by h0==0, unused
    const float* lstm_b_ih = (const float*)d_in[10];
    const float* lstm_b_hh = (const float*)d_in[11];
    const float* lin_w     = (const float*)d_in[12];
    const float* lin_b     = (const float*)d_in[13];

    int n = in_sizes[0] / 4;      // 100000
    int E = in_sizes[2];          // 6400000
    int P = (n + NBL - 1) >> NBL_SHIFT;

    // fast-path workspace layout (bytes):
    //   rec[E] uint2 | m[n*4] f32 | hist2d[B1*P] u32 | total[P] u32 | base[P] u32
    size_t off_rec  = 0;
    size_t off_m    = off_rec + (size_t)E * 8;
    size_t off_h2d  = off_m + (size_t)n * 16;
    size_t off_tot  = off_h2d + (size_t)B1 * P * 4;
    size_t off_base = off_tot + (size_t)P * 4;
    size_t need     = off_base + (size_t)P * 4;

    bool fast = (ws_size >= need) && (n <= (1 << SRC_BITS)) && (P <= PMAX);

    if (fast) {
        uint2*    rec    = (uint2*)((char*)d_ws + off_rec);
        float*    m      = (float*)((char*)d_ws + off_m);
        unsigned* h2d    = (unsigned*)((char*)d_ws + off_h2d);
        unsigned* totalv = (unsigned*)((char*)d_ws + off_tot);
        unsigned* basev  = (unsigned*)((char*)d_ws + off_base);

        const int* srcp = ei;
        const int* dstp = ei + E;
        int chunk = (E + B1 - 1) / B1;

        compute_m_kernel<<<(n + 255) / 256, 256, 0, stream>>>(x, ggc_w, m, n);
        hist_kernel<<<B1, 256, 0, stream>>>(dstp, E, chunk, P, h2d);
        colscan_kernel<<<(P + 3) / 4, 256, 0, stream>>>(h2d, P, totalv);
        scan_kernel<<<1, PMAX, 0, stream>>>(totalv, P, basev);
        scatter_kernel<<<B1, 256, 0, stream>>>(srcp, dstp, ew, E, chunk, P,
                                               h2d, basev, rec);
        bucket_tail_kernel<<<P, BT, 0, stream>>>(
            rec, basev, totalv, m, x,
            gru_w_ih, gru_w_hh, gru_b_ih, gru_b_hh,
            lstm_w_ih, lstm_b_ih, lstm_b_hh, lin_w, lin_b,
            (float*)d_out, n);
    } else {
        // fallback: proven R2 atomic path
        float* agg = (float*)d_ws;
        float* cnt = agg + (size_t)n * 4;
        float* m   = cnt + n;
        hipMemsetAsync(d_ws, 0, (size_t)n * 5 * sizeof(float), stream);
        compute_m_kernel<<<(n + 255) / 256, 256, 0, stream>>>(x, ggc_w, m, n);
        edge_agg_kernel<<<(E + 255) / 256, 256, 0, stream>>>(ei, ew, m, agg, cnt, E);
        node_tail_kernel<<<(n + 255) / 256, 256, 0, stream>>>(
            x, agg, cnt, gru_w_ih, gru_w_hh, gru_b_ih, gru_b_hh,
            lstm_w_ih, lstm_b_ih, lstm_b_hh, lin_w, lin_b,
            (float*)d_out, n);
    }
}